// Round 15
// baseline (4554.367 us; speedup 1.0000x reference)
//
#include <hip/hip_runtime.h>
#include <hip/hip_fp16.h>

#define T_ 1000

typedef float v2f __attribute__((ext_vector_type(2)));
typedef __fp16 h2t __attribute__((ext_vector_type(2)));
typedef __fp16 h8v_t __attribute__((ext_vector_type(8)));
typedef float f32x4 __attribute__((ext_vector_type(4)));

// barrier with LDS visibility but NO vmcnt drain (keeps prefetch/stores in flight)
#define REC_BARRIER() asm volatile("s_waitcnt lgkmcnt(0)\n\ts_barrier" ::: "memory")

__device__ __forceinline__ float sigf(float x) { return 1.0f / (1.0f + __expf(-x)); }
__device__ __forceinline__ float tanh_fast(float x) { return 1.0f - 2.0f / (1.0f + __expf(2.0f * x)); }
__device__ __forceinline__ float dot4(float4 a, float4 b) {
  return a.x * b.x + a.y * b.y + a.z * b.z + a.w * b.w;
}
__device__ __forceinline__ void pkfma(v2f& acc, float4 w, float4 v) {
  v2f wl; wl[0] = w.x; wl[1] = w.y;
  v2f wh; wh[0] = w.z; wh[1] = w.w;
  v2f vl; vl[0] = v.x; vl[1] = v.y;
  v2f vh; vh[0] = v.z; vh[1] = v.w;
  acc += wl * vl;
  acc += wh * vh;
}
__device__ __forceinline__ unsigned short f2bf(float f) {
  unsigned u = __float_as_uint(f);
  u = (u + 0x7fffu + ((u >> 16) & 1u)) >> 16;  // RNE
  return (unsigned short)u;
}
__device__ __forceinline__ float bf2f(unsigned short h) {
  return __uint_as_float(((unsigned)h) << 16);
}
__device__ __forceinline__ float4 bf4_to_f4(ushort4 u) {
  float4 r;
  r.x = bf2f(u.x); r.y = bf2f(u.y); r.z = bf2f(u.z); r.w = bf2f(u.w);
  return r;
}

__global__ void bail_kernel(float* out, int n) {
  for (int i = threadIdx.x; i < n; i += 256) out[i] = 0.0f;
}

// ---------------- LN stats: per row (mu, rs) ----------------
__global__ __launch_bounds__(256) void ln_stats_kernel(const float* __restrict__ x,
                                                       float* __restrict__ mu_arr,
                                                       float* __restrict__ rs_arr) {
  const int lane = threadIdx.x & 63;
  const int w = threadIdx.x >> 6;
  const long row = (long)blockIdx.x * 4 + w;
  float v = (lane < 40) ? x[row * 40 + lane] : 0.0f;
  float s1 = v, s2 = v * v;
  for (int m = 32; m; m >>= 1) {
    s1 += __shfl_xor(s1, m, 64);
    s2 += __shfl_xor(s2, m, 64);
  }
  if (lane == 0) {
    const float mu = s1 * (1.0f / 40.0f);
    const float var = s2 * (1.0f / 40.0f) - mu * mu;
    mu_arr[row] = mu;
    rs_arr[row] = rsqrtf(var + 1e-5f);
  }
}

// ---------------- xw0 chunk = LN(x)[slice] @ Wih0^T  (LN fused; f16 out) ----------------
__global__ __launch_bounds__(256, 2) void gemm_xw0(
    const float* __restrict__ x,
    const float* __restrict__ mu_arr, const float* __restrict__ rs_arr,
    const float* __restrict__ ln_g, const float* __restrict__ ln_b,
    const float* __restrict__ Wf, const float* __restrict__ Wb,
    __fp16* __restrict__ xwf, __fp16* __restrict__ xwb,
    int Tc, int t0f, int t0b) {
  __shared__ float As[64 * 44];
  __shared__ float Bs[128 * 44];
  const int tid = threadIdx.x;
  const int tx = tid & 15, ty = tid >> 4;
  const int r0 = blockIdx.x * 64;
  const int jt = blockIdx.y;
  const int dir = jt >> 2, nh = jt & 3;
  const float* __restrict__ W = dir ? Wb : Wf;
  __fp16* __restrict__ out = dir ? xwb : xwf;
  const int jbase = nh * 128;
  const int t0 = dir ? t0b : t0f;

  float4* As4 = (float4*)As;
  float4* Bs4 = (float4*)Bs;
  {  // A stage with fused LayerNorm
    const int row = tid >> 2;
    const int t4 = tid & 3;
    const int r = r0 + row;
    const int br = r / Tc;
    const long xrow = (long)br * T_ + t0 + (r - br * Tc);
    const float mu = mu_arr[xrow];
    const float rs = rs_arr[xrow];
#pragma unroll
    for (int m = 0; m < 3; ++m) {
      const int k4 = t4 + m * 4;
      if (k4 < 10) {
        const float4 v = *(const float4*)&x[xrow * 40 + k4 * 4];
        const float4 g4 = *(const float4*)&ln_g[k4 * 4];
        const float4 b4 = *(const float4*)&ln_b[k4 * 4];
        float4 xn;
        xn.x = (v.x - mu) * rs * g4.x + b4.x;
        xn.y = (v.y - mu) * rs * g4.y + b4.y;
        xn.z = (v.z - mu) * rs * g4.z + b4.z;
        xn.w = (v.w - mu) * rs * g4.w + b4.w;
        As4[row * 11 + k4] = xn;
      }
    }
  }
  {  // B stage
    const int row = tid & 127;
    const int h = tid >> 7;
#pragma unroll
    for (int m = 0; m < 5; ++m) {
      const int k4 = h + m * 2;
      Bs4[row * 11 + k4] = *(const float4*)&W[(long)(jbase + row) * 40 + k4 * 4];
    }
  }
  __syncthreads();

  v2f acc2[4][8];
#pragma unroll
  for (int r = 0; r < 4; ++r)
#pragma unroll
    for (int c2 = 0; c2 < 8; ++c2) acc2[r][c2] = 0.0f;
#pragma unroll 1
  for (int k4 = 0; k4 < 10; ++k4) {
    float4 av[4];
#pragma unroll
    for (int r = 0; r < 4; ++r) av[r] = As4[(ty * 4 + r) * 11 + k4];
#pragma unroll
    for (int c2 = 0; c2 < 8; ++c2) {
      const float4 bv = Bs4[(tx + 16 * c2) * 11 + k4];
#pragma unroll
      for (int r = 0; r < 4; ++r) pkfma(acc2[r][c2], av[r], bv);
    }
  }
#pragma unroll
  for (int r = 0; r < 4; ++r) {
    const long ob = (long)(r0 + ty * 4 + r) * 512 + jbase + tx;
#pragma unroll
    for (int c2 = 0; c2 < 8; ++c2) out[ob + c2 * 16] = (__fp16)(acc2[r][c2][0] + acc2[r][c2][1]);
  }
}

// ---------------- MFMA-batched recurrence: 8 chains per block, 32 blocks ----------------
// Per step: gates = Whh(f16, A-fragments in regs) @ h(f16, LDS) via 16x mfma_f32_16x16x32_f16
// per wave (wave w owns gate-rows [64w,64w+64), FULL K=128 -> no cross-wave reduce).
// D -> gacc LDS -> combine phase (2 cells/thread): + xw + bias, gates, c/h update,
// h -> swizzled f16 LDS (B operand) + global store. 2 lgkmcnt-barriers/step.
// A frag: lane row=l&15, k=(l>>4)*8+j. B frag: col(batch)=l&15, same k. D: col=l&15,
// row=(l>>4)*4+reg (m89-verified). h16 rows 8..15 stay zero (B=8 < N=16).
__global__ __launch_bounds__(512) void rec_mfma(
    const __fp16* __restrict__ xw_f, const __fp16* __restrict__ xw_b,
    const float* __restrict__ Whh_f, const float* __restrict__ Whh_b,
    const float* __restrict__ bih_f, const float* __restrict__ bhh_f,
    const float* __restrict__ bih_b, const float* __restrict__ bhh_b,
    float* __restrict__ h0out, unsigned short* __restrict__ h1out, int out_bf16,
    float* __restrict__ state, int Tc, int t0f, int t0b, int first) {
  const int tid = threadIdx.x;
  const int w = tid >> 6;       // wave 0..7
  const int l = tid & 63;
  const int al = l & 15;        // A row / B col(batch) / D col
  const int kg = l >> 4;        // k-group 0..3
  const int dir = blockIdx.x & 1;
  const int bg = blockIdx.x >> 1;   // 0..15
  const int brow0 = bg * 8;
  const __fp16* __restrict__ xw = dir ? xw_b : xw_f;
  const float* __restrict__ Whh = dir ? Whh_b : Whh_f;
  const float* __restrict__ bih = dir ? bih_b : bih_f;
  const float* __restrict__ bhh = dir ? bhh_b : bhh_f;
  const int t0 = dir ? t0b : t0f;

  // A fragments (f16 weights, 64 VGPR): wA[mt][kt], row = w*64+mt*16+al, k = kt*32+kg*8+j
  h8v_t wA[4][4];
#pragma unroll
  for (int mt = 0; mt < 4; ++mt) {
    const int grow = w * 64 + mt * 16 + al;
#pragma unroll
    for (int kt = 0; kt < 4; ++kt) {
      const int k0 = kt * 32 + kg * 8;
      const float4 wa = *(const float4*)&Whh[(long)grow * 128 + k0];
      const float4 wb = *(const float4*)&Whh[(long)grow * 128 + k0 + 4];
      h8v_t v;
      v[0] = (__fp16)wa.x; v[1] = (__fp16)wa.y; v[2] = (__fp16)wa.z; v[3] = (__fp16)wa.w;
      v[4] = (__fp16)wb.x; v[5] = (__fp16)wb.y; v[6] = (__fp16)wb.z; v[7] = (__fp16)wb.w;
      wA[mt][kt] = v;
    }
  }
  // combine-phase ids: thread handles unit u2, batches 2q and 2q+1
  const int u2 = tid & 127;
  const int q = tid >> 7;  // 0..3
  float bsum[4];
#pragma unroll
  for (int g = 0; g < 4; ++g) bsum[g] = bih[g * 128 + u2] + bhh[g * 128 + u2];

  // h16 row stride 136 f16 = 272B (16B-aligned); k-chunk position swizzled by batch:
  // chunk c of batch b stored at pos ((c+b)&3)*32 -> B-frag b128 reads ~2-way banks.
  __shared__ __align__(16) __fp16 h16[2][16][136];
  __shared__ float gacc[512][9];  // [gate-row][batch], pad 9

  float* sblk = state + (long)blockIdx.x * 2048;  // 1024 h + 1024 c
  for (int i = tid; i < 2 * 16 * 136; i += 512) ((__fp16*)h16)[i] = (__fp16)0.0f;
  float cc0 = 0.0f, cc1 = 0.0f;
  __syncthreads();
  if (!first) {
    for (int i = tid; i < 1024; i += 512) {
      const int b = i >> 7, uu = i & 127;
      h16[0][b][(((uu >> 5) + b) & 3) * 32 + (uu & 31)] = (__fp16)sblk[i];
    }
    cc0 = sblk[1024 + (2 * q) * 128 + u2];
    cc1 = sblk[1024 + (2 * q + 1) * 128 + u2];
  }
  // xw prefetch for step 0: xwreg[g*2+j] for gate g, batch 2q+j
  float xwreg[8];
  {
    const int tr0 = dir ? (Tc - 1) : 0;
#pragma unroll
    for (int g = 0; g < 4; ++g)
#pragma unroll
      for (int j = 0; j < 2; ++j) {
        const int b = 2 * q + j;
        xwreg[g * 2 + j] = (float)xw[((long)(brow0 + b) * Tc + tr0) * 512 + g * 128 + u2];
      }
  }
  __syncthreads();

  for (int s = 0; s < Tc; ++s) {
    const int rq = s & 1, wq = rq ^ 1;
    // ---- MFMA phase ----
    h8v_t Bf[4];
#pragma unroll
    for (int kt = 0; kt < 4; ++kt)
      Bf[kt] = *(const h8v_t*)&h16[rq][al][(((kt + al) & 3) << 5) + (kg << 3)];
#pragma unroll
    for (int mt = 0; mt < 4; ++mt) {
      f32x4 acc = {0.0f, 0.0f, 0.0f, 0.0f};
#pragma unroll
      for (int kt = 0; kt < 4; ++kt)
        acc = __builtin_amdgcn_mfma_f32_16x16x32_f16(wA[mt][kt], Bf[kt], acc, 0, 0, 0);
      if (al < 8) {
#pragma unroll
        for (int r = 0; r < 4; ++r)
          gacc[w * 64 + mt * 16 + kg * 4 + r][al] = acc[r];
      }
    }
    REC_BARRIER();  // gacc ready
    // ---- combine phase ----
    const int tglob = t0 + (dir ? (Tc - 1 - s) : s);
#pragma unroll
    for (int j = 0; j < 2; ++j) {
      const int b = 2 * q + j;
      const float gi = gacc[u2][b]       + xwreg[0 * 2 + j] + bsum[0];
      const float gf = gacc[128 + u2][b] + xwreg[1 * 2 + j] + bsum[1];
      const float gg = gacc[256 + u2][b] + xwreg[2 * 2 + j] + bsum[2];
      const float go = gacc[384 + u2][b] + xwreg[3 * 2 + j] + bsum[3];
      const float ig = sigf(gi);
      const float fg = sigf(gf);
      const float g2 = tanh_fast(gg);
      const float og = sigf(go);
      float c = j ? cc1 : cc0;
      c = fg * c + ig * g2;
      if (j) cc1 = c; else cc0 = c;
      const float hv = og * tanh_fast(c);
      h16[wq][b][(((u2 >> 5) + b) & 3) * 32 + (u2 & 31)] = (__fp16)hv;
      const long oidx = ((long)(brow0 + b) * T_ + tglob) * 256 + dir * 128 + u2;
      if (out_bf16) h1out[oidx] = f2bf(hv);
      else          h0out[oidx] = hv;
    }
    {  // prefetch next step's xw (in flight across barrier)
      const int sn = s + 1;
      if (sn < Tc) {
        const int tr = dir ? (Tc - 1 - sn) : sn;
#pragma unroll
        for (int g = 0; g < 4; ++g)
#pragma unroll
          for (int j = 0; j < 2; ++j) {
            const int b = 2 * q + j;
            xwreg[g * 2 + j] = (float)xw[((long)(brow0 + b) * Tc + tr) * 512 + g * 128 + u2];
          }
      }
    }
    REC_BARRIER();  // h16[wq] ready; gacc reusable
  }
  // save state (h from final buffer, c from regs)
  const int fin = Tc & 1;
  for (int i = tid; i < 1024; i += 512) {
    const int b = i >> 7, uu = i & 127;
    sblk[i] = (float)h16[fin][b][(((uu >> 5) + b) & 3) * 32 + (uu & 31)];
  }
  sblk[1024 + (2 * q) * 128 + u2] = cc0;
  sblk[1024 + (2 * q + 1) * 128 + u2] = cc1;
}

// ---------------- xw1 chunk GEMM: tile M=64 x N=128, K=256, micro 4x8, f16 out ----------------
__global__ __launch_bounds__(256, 2) void gemm_xw1(
    const float* __restrict__ h0,
    const float* __restrict__ Wf, const float* __restrict__ Wb,
    __fp16* __restrict__ xwf, __fp16* __restrict__ xwb,
    int Tc, int t0f, int t0b) {
  __shared__ float As[64 * 36];
  __shared__ float Bs[128 * 36];
  __shared__ int rowbase[64];
  const int tid = threadIdx.x;
  const int tx = tid & 15, ty = tid >> 4;
  const int r0 = blockIdx.x * 64;
  const int jt = blockIdx.y;
  const int dir = jt >> 2;
  const int nh = jt & 3;
  const float* __restrict__ W = dir ? Wb : Wf;
  __fp16* __restrict__ out = dir ? xwb : xwf;
  const int jbase = nh * 128;
  const int t0 = dir ? t0b : t0f;

  if (tid < 64) {
    const int r = r0 + tid;
    const int br = r / Tc;
    rowbase[tid] = br * T_ + t0 + (r - br * Tc);
  }

  float4* As4 = (float4*)As;
  float4* Bs4 = (float4*)Bs;
  v2f acc2[4][8];
#pragma unroll
  for (int r = 0; r < 4; ++r)
#pragma unroll
    for (int c2 = 0; c2 < 8; ++c2) acc2[r][c2] = 0.0f;
#pragma unroll 1
  for (int kk = 0; kk < 8; ++kk) {
    __syncthreads();
#pragma unroll
    for (int i = 0; i < 2; ++i) {
      const int q = tid + i * 256;
      const int row = q >> 3, k4 = q & 7;
      As4[row * 9 + k4] = *(const float4*)&h0[(long)rowbase[row] * 256 + kk * 32 + k4 * 4];
    }
#pragma unroll
    for (int i = 0; i < 4; ++i) {
      const int q = tid + i * 256;
      const int row = q >> 3, k4 = q & 7;
      Bs4[row * 9 + k4] = *(const float4*)&W[(long)(jbase + row) * 256 + kk * 32 + k4 * 4];
    }
    __syncthreads();
#pragma unroll 1
    for (int k4 = 0; k4 < 8; ++k4) {
      float4 av[4];
#pragma unroll
      for (int r = 0; r < 4; ++r) av[r] = As4[(ty * 4 + r) * 9 + k4];
#pragma unroll
      for (int c2 = 0; c2 < 8; ++c2) {
        const float4 bv = Bs4[(tx + 16 * c2) * 9 + k4];
#pragma unroll
        for (int r = 0; r < 4; ++r) pkfma(acc2[r][c2], av[r], bv);
      }
    }
  }
#pragma unroll
  for (int r = 0; r < 4; ++r) {
    const long ob = (long)(r0 + ty * 4 + r) * 512 + jbase + tx;
#pragma unroll
    for (int c2 = 0; c2 < 8; ++c2) out[ob + c2 * 16] = (__fp16)(acc2[r][c2][0] + acc2[r][c2][1]);
  }
}

// ---------------- attention scores ----------------
__global__ __launch_bounds__(256, 2) void score_kernel(
    const unsigned short* __restrict__ h1b, const float* __restrict__ W1,
    const float* __restrict__ b1, const float* __restrict__ w2,
    float* __restrict__ scores) {
  __shared__ float As[64 * 36];
  __shared__ float Bs[128 * 36];
  const int tid = threadIdx.x;
  const int tx = tid & 15, ty = tid >> 4;
  const long r0 = (long)blockIdx.x * 64;

  float4* As4 = (float4*)As;
  float4* Bs4 = (float4*)Bs;
  v2f acc2[4][8];
#pragma unroll
  for (int r = 0; r < 4; ++r)
#pragma unroll
    for (int c2 = 0; c2 < 8; ++c2) acc2[r][c2] = 0.0f;
#pragma unroll 1
  for (int kk = 0; kk < 8; ++kk) {
    __syncthreads();
#pragma unroll
    for (int i = 0; i < 2; ++i) {
      const int q = tid + i * 256;
      const int row = q >> 3, k4 = q & 7;
      const ushort4 uv = *(const ushort4*)&h1b[(r0 + row) * 256 + kk * 32 + k4 * 4];
      As4[row * 9 + k4] = bf4_to_f4(uv);
    }
#pragma unroll
    for (int i = 0; i < 4; ++i) {
      const int q = tid + i * 256;
      const int row = q >> 3, k4 = q & 7;
      Bs4[row * 9 + k4] = *(const float4*)&W1[(long)row * 256 + kk * 32 + k4 * 4];
    }
    __syncthreads();
#pragma unroll 1
    for (int k4 = 0; k4 < 8; ++k4) {
      float4 av[4];
#pragma unroll
      for (int r = 0; r < 4; ++r) av[r] = As4[(ty * 4 + r) * 9 + k4];
#pragma unroll
      for (int c2 = 0; c2 < 8; ++c2) {
        const float4 bv = Bs4[(tx + 16 * c2) * 9 + k4];
#pragma unroll
        for (int r = 0; r < 4; ++r) pkfma(acc2[r][c2], av[r], bv);
      }
    }
  }
#pragma unroll
  for (int r = 0; r < 4; ++r) {
    float s = 0.0f;
#pragma unroll
    for (int c2 = 0; c2 < 8; ++c2) {
      const int col = tx + 16 * c2;
      s += tanh_fast(acc2[r][c2][0] + acc2[r][c2][1] + b1[col]) * w2[col];
    }
#pragma unroll
    for (int m = 1; m < 16; m <<= 1) s += __shfl_xor(s, m, 16);
    if (tx == 0) scores[r0 + ty * 4 + r] = s;
  }
}

// ---------------- softmax over T + ctx + MLP head ----------------
__global__ __launch_bounds__(256, 2) void head_kernel(
    const float* __restrict__ scores, const unsigned short* __restrict__ h1b,
    const float* __restrict__ fW1, const float* __restrict__ fb1,
    const float* __restrict__ fW2, const float* __restrict__ fb2,
    float* __restrict__ outp) {
  const int b = blockIdx.x, tid = threadIdx.x;
  __shared__ float wls[1000];
  __shared__ float red[8];
  __shared__ __align__(16) float ctx[256];
  __shared__ __align__(16) float hid[128];

  float sv[4];
  float mx = -1e30f;
#pragma unroll
  for (int i = 0; i < 4; ++i) {
    const int t = tid + i * 256;
    sv[i] = (t < 1000) ? scores[b * 1000 + t] : -1e30f;
    mx = fmaxf(mx, sv[i]);
  }
  for (int m = 32; m; m >>= 1) mx = fmaxf(mx, __shfl_xor(mx, m, 64));
  if ((tid & 63) == 0) red[tid >> 6] = mx;
  __syncthreads();
  mx = fmaxf(fmaxf(red[0], red[1]), fmaxf(red[2], red[3]));
  float se = 0.0f;
#pragma unroll
  for (int i = 0; i < 4; ++i) {
    const int t = tid + i * 256;
    if (t < 1000) {
      const float e = __expf(sv[i] - mx);
      wls[t] = e;
      se += e;
    }
  }
  for (int m = 32; m; m >>= 1) se += __shfl_xor(se, m, 64);
  if ((tid & 63) == 0) red[4 + (tid >> 6)] = se;
  __syncthreads();
  const float rinv = 1.0f / (red[4] + red[5] + red[6] + red[7]);

  float a = 0.0f;
  const unsigned short* hb = h1b + (long)b * T_ * 256 + tid;
  for (int t = 0; t < T_; ++t) a = fmaf(wls[t], bf2f(hb[t * 256]), a);
  ctx[tid] = a * rinv;
  __syncthreads();
  if (tid < 128) {
    float s = fb1[tid];
    const float4* wr = (const float4*)&fW1[tid * 256];
    const float4* cc = (const float4*)ctx;
#pragma unroll
    for (int f = 0; f < 64; ++f) s += dot4(wr[f], cc[f]);
    hid[tid] = fmaxf(s, 0.0f);
  }
  __syncthreads();
  if (tid < 8) {
    float s = fb2[tid];
    const float4* wr = (const float4*)&fW2[tid * 128];
    const float4* hh = (const float4*)hid;
#pragma unroll
    for (int f = 0; f < 32; ++f) s += dot4(wr[f], hh[f]);
    outp[b * 8 + tid] = s;
  }
}

extern "C" void kernel_launch(void* const* d_in, const int* in_sizes, int n_in,
                              void* d_out, int out_size, void* d_ws, size_t ws_size,
                              hipStream_t stream) {
  (void)in_sizes; (void)n_in; (void)out_size;
  const float* x       = (const float*)d_in[0];
  const float* ln_g    = (const float*)d_in[1];
  const float* ln_b    = (const float*)d_in[2];
  const float* Wih_f0  = (const float*)d_in[3];
  const float* Whh_f0  = (const float*)d_in[4];
  const float* bih_f0  = (const float*)d_in[5];
  const float* bhh_f0  = (const float*)d_in[6];
  const float* Wih_b0  = (const float*)d_in[7];
  const float* Whh_b0  = (const float*)d_in[8];
  const float* bih_b0  = (const float*)d_in[9];
  const float* bhh_b0  = (const float*)d_in[10];
  const float* Wih_f1  = (const float*)d_in[11];
  const float* Whh_f1  = (const float*)d_in[12];
  const float* bih_f1  = (const float*)d_in[13];
  const float* bhh_f1  = (const float*)d_in[14];
  const float* Wih_b1  = (const float*)d_in[15];
  const float* Whh_b1  = (const float*)d_in[16];
  const float* bih_b1  = (const float*)d_in[17];
  const float* bhh_b1  = (const float*)d_in[18];
  const float* attn_W1 = (const float*)d_in[19];
  const float* attn_b1 = (const float*)d_in[20];
  const float* attn_w2 = (const float*)d_in[21];
  const float* fc_W1   = (const float*)d_in[22];
  const float* fc_b1   = (const float*)d_in[23];
  const float* fc_W2   = (const float*)d_in[24];
  const float* fc_b2   = (const float*)d_in[25];

  char* base = (char*)d_ws;
  size_t off = 0;
  auto alloc = [&](size_t bytes) {
    char* ptr = base + off;
    off += (bytes + 255) & ~(size_t)255;
    return ptr;
  };
  float*          h0    = (float*)alloc(32768000ull * 4);          // 131.1 MB
  unsigned short* h1b   = (unsigned short*)alloc(32768000ull * 2); //  65.5 MB
  float*          state = (float*)alloc(65536ull * 4);
  float*          scor  = (float*)alloc(128000ull * 4);
  float*          mu_a  = (float*)alloc(128000ull * 4);
  float*          rs_a  = (float*)alloc(128000ull * 4);

  const size_t rem = (ws_size > off) ? (ws_size - off) : 0;
  static const int cands[16] = {1000, 500, 250, 200, 125, 100, 50, 40, 25, 20, 10, 8, 5, 4, 2, 1};
  int Tc = 0;
  for (int ci = 0; ci < 16; ++ci) {
    // xw buffer: 65536 values/step/dir x 2 dirs x 2B (f16) = 262144 B per step
    if (262144ull * (size_t)cands[ci] <= rem) { Tc = cands[ci]; break; }
  }
  if (Tc == 0) {
    bail_kernel<<<dim3(1), dim3(256), 0, stream>>>((float*)d_out, 1024);
    return;
  }
  __fp16* xwf = (__fp16*)(base + off);
  __fp16* xwb = xwf + 65536L * Tc;

  ln_stats_kernel<<<dim3(32000), dim3(256), 0, stream>>>(x, mu_a, rs_a);
  const int nch = T_ / Tc;
  // Layer 0: xw0 chunk GEMM (LN fused) + MFMA recurrence (f32 h0 out)
  for (int ch = 0; ch < nch; ++ch) {
    const int t0f = ch * Tc;
    const int t0b = T_ - (ch + 1) * Tc;
    gemm_xw0<<<dim3(2 * Tc, 8), dim3(256), 0, stream>>>(x, mu_a, rs_a, ln_g, ln_b,
                                                        Wih_f0, Wih_b0, xwf, xwb, Tc, t0f, t0b);
    rec_mfma<<<dim3(32), dim3(512), 0, stream>>>(xwf, xwb, Whh_f0, Whh_b0,
                                                 bih_f0, bhh_f0, bih_b0, bhh_b0,
                                                 h0, h1b, 0, state, Tc, t0f, t0b,
                                                 (ch == 0) ? 1 : 0);
  }
  // Layer 1: xw1 chunk GEMM + MFMA recurrence (bf16 h1 out)
  for (int ch = 0; ch < nch; ++ch) {
    const int t0f = ch * Tc;
    const int t0b = T_ - (ch + 1) * Tc;
    gemm_xw1<<<dim3(2 * Tc, 8), dim3(256), 0, stream>>>(h0, Wih_f1, Wih_b1, xwf, xwb, Tc, t0f, t0b);
    rec_mfma<<<dim3(32), dim3(512), 0, stream>>>(xwf, xwb, Whh_f1, Whh_b1,
                                                 bih_f1, bhh_f1, bih_b1, bhh_b1,
                                                 h0, h1b, 1, state, Tc, t0f, t0b,
                                                 (ch == 0) ? 1 : 0);
  }
  score_kernel<<<dim3(2000), dim3(256), 0, stream>>>(h1b, attn_W1, attn_b1, attn_w2, scor);
  head_kernel<<<dim3(128), dim3(256), 0, stream>>>(scor, h1b, fc_W1, fc_b1, fc_W2, fc_b2,
                                                   (float*)d_out);
}